// Round 2
// baseline (1839.549 us; speedup 1.0000x reference)
//
#include <hip/hip_runtime.h>

#define B_  2
#define T_  2048
#define DM  1024
#define DP  4288
#define DI  2048
#define DS  64

__device__ __forceinline__ float siluf_(float x) { return x / (1.f + __expf(-x)); }
__device__ __forceinline__ float softplusf_(float x) {
  return fmaxf(x, 0.f) + log1pf(__expf(-fabsf(x)));
}
__device__ __forceinline__ float rlane_(float v, int l) {
  return __uint_as_float(__builtin_amdgcn_readlane(__float_as_uint(v), l));
}

// ---------------------------------------------------------------- in_proj GEMM
// P[m,n] = sum_k X[m,k] * W[n,k];  M=4096, N=4288, K=1024 (both K-major, "NT")
__global__ __launch_bounds__(256) void k_inproj(const float* __restrict__ X,
                                                const float* __restrict__ W,
                                                float* __restrict__ P) {
  __shared__ float As[16][68];
  __shared__ float Bs[16][68];
  const int m0 = blockIdx.x * 64, n0 = blockIdx.y * 64;
  const int tid = threadIdx.x;
  const int tm = tid & 15, tn = tid >> 4;
  const int lr = tid >> 2, lc = (tid & 3) << 2;
  const float* Xp = X + (size_t)(m0 + lr) * DM + lc;
  const float* Wp = W + (size_t)(n0 + lr) * DM + lc;
  float acc[4][4] = {};
  for (int k0 = 0; k0 < DM; k0 += 16) {
    const float4 av = *(const float4*)(Xp + k0);
    const float4 bv = *(const float4*)(Wp + k0);
    __syncthreads();
    As[lc + 0][lr] = av.x; As[lc + 1][lr] = av.y;
    As[lc + 2][lr] = av.z; As[lc + 3][lr] = av.w;
    Bs[lc + 0][lr] = bv.x; Bs[lc + 1][lr] = bv.y;
    Bs[lc + 2][lr] = bv.z; Bs[lc + 3][lr] = bv.w;
    __syncthreads();
#pragma unroll
    for (int kk = 0; kk < 16; ++kk) {
      float a_[4], b_[4];
#pragma unroll
      for (int u = 0; u < 4; ++u) {
        a_[u] = As[kk][(tm << 2) + u];
        b_[u] = Bs[kk][(tn << 2) + u];
      }
#pragma unroll
      for (int mi = 0; mi < 4; ++mi)
#pragma unroll
        for (int ni = 0; ni < 4; ++ni)
          acc[mi][ni] = fmaf(a_[mi], b_[ni], acc[mi][ni]);
    }
  }
  float* Crow = P + (size_t)(m0 + (tm << 2)) * DP + n0 + (tn << 2);
#pragma unroll
  for (int mi = 0; mi < 4; ++mi)
    *(float4*)(Crow + (size_t)mi * DP) =
        make_float4(acc[mi][0], acc[mi][1], acc[mi][2], acc[mi][3]);
}

// ------------------------------------------------- depthwise conv + SiLU (+z)
// xcT[b,i,t] = silu(conv_b[i] + sum_{k<4} conv_w[i,k] * x_inner[b,t-3+k,i])
// zsT[b,i,t] = silu(proj[b,t,DI+i])            (both stored transposed (b,i,t))
__global__ __launch_bounds__(256) void k_conv(const float* __restrict__ P,
                                              const float* __restrict__ cw,
                                              const float* __restrict__ cb,
                                              float* __restrict__ xcT,
                                              float* __restrict__ zsT) {
  __shared__ float L[64][69];  // [i][r]
  const int b = blockIdx.z;
  const int t0 = blockIdx.x * 64, i0 = blockIdx.y * 64;
  const int tid = threadIdx.x;
  const int li = tid & 63, r0 = tid >> 6;
  const float* pb = P + (size_t)b * T_ * DP;
  for (int r = r0; r < 67; r += 4) {
    const int t = t0 - 3 + r;
    L[li][r] = (t >= 0) ? pb[(size_t)t * DP + i0 + li] : 0.f;
  }
  __syncthreads();
  const int i = tid >> 2, tg = tid & 3;
  const float4 w = *(const float4*)(cw + (size_t)(i0 + i) * 4);
  const float bias = cb[i0 + i];
  float res[16];
#pragma unroll
  for (int j = 0; j < 16; ++j) {
    const int t = (tg << 4) + j;
    float a = bias;
    a = fmaf(w.x, L[i][t + 0], a);
    a = fmaf(w.y, L[i][t + 1], a);
    a = fmaf(w.z, L[i][t + 2], a);
    a = fmaf(w.w, L[i][t + 3], a);
    res[j] = siluf_(a);
  }
  float* dst = xcT + (size_t)(b * DI + i0 + i) * T_ + t0 + (tg << 4);
#pragma unroll
  for (int j = 0; j < 16; j += 4)
    *(float4*)(dst + j) = make_float4(res[j], res[j + 1], res[j + 2], res[j + 3]);

  // silu(z) transpose pass
  __syncthreads();
  for (int r = r0; r < 64; r += 4)
    L[li][r] = pb[(size_t)(t0 + r) * DP + DI + i0 + li];
  __syncthreads();
#pragma unroll
  for (int j = 0; j < 16; ++j) res[j] = siluf_(L[i][(tg << 4) + j]);
  float* dst2 = zsT + (size_t)(b * DI + i0 + i) * T_ + t0 + (tg << 4);
#pragma unroll
  for (int j = 0; j < 16; j += 4)
    *(float4*)(dst2 + j) = make_float4(res[j], res[j + 1], res[j + 2], res[j + 3]);
}

// ------------------------------------------------------- delta GEMM + softplus
// dtT[b,i,t] = softplus(dtb[i] + sum_{r<64} proj[b,t,4224+r] * dtw[i,r])
__global__ __launch_bounds__(256) void k_dt(const float* __restrict__ P,
                                            const float* __restrict__ dtw,
                                            const float* __restrict__ dtb,
                                            float* __restrict__ dtT) {
  __shared__ float As[64][69];  // [t][r]
  __shared__ float Bs[64][69];  // [i][r]
  const int b = blockIdx.z;
  const int t0 = blockIdx.x * 64, i0 = blockIdx.y * 64;
  const int tid = threadIdx.x;
  const int row = tid >> 2, c0 = (tid & 3) << 4;
  const float* pa = P + (size_t)(b * T_ + t0 + row) * DP + (DP - 64) + c0;
  const float* pbm = dtw + (size_t)(i0 + row) * 64 + c0;
#pragma unroll
  for (int j = 0; j < 16; j += 4) {
    *(float4*)&As[row][c0 + j] = *(const float4*)(pa + j);
    *(float4*)&Bs[row][c0 + j] = *(const float4*)(pbm + j);
  }
  __syncthreads();
  const int tm = tid & 15, tn = tid >> 4;
  float acc[4][4] = {};  // [ni][mi]
#pragma unroll 4
  for (int r = 0; r < 64; ++r) {
    float a_[4], b_[4];
#pragma unroll
    for (int u = 0; u < 4; ++u) {
      a_[u] = As[(tm << 2) + u][r];
      b_[u] = Bs[(tn << 2) + u][r];
    }
#pragma unroll
    for (int ni = 0; ni < 4; ++ni)
#pragma unroll
      for (int mi = 0; mi < 4; ++mi)
        acc[ni][mi] = fmaf(a_[mi], b_[ni], acc[ni][mi]);
  }
#pragma unroll
  for (int ni = 0; ni < 4; ++ni) {
    const int i = i0 + (tn << 2) + ni;
    const float bias = dtb[i];
    float4 o;
    o.x = softplusf_(acc[ni][0] + bias);
    o.y = softplusf_(acc[ni][1] + bias);
    o.z = softplusf_(acc[ni][2] + bias);
    o.w = softplusf_(acc[ni][3] + bias);
    *(float4*)&dtT[(size_t)(b * DI + i) * T_ + t0 + (tm << 2)] = o;
  }
}

// ------------------------------------------------------------- selective scan
// one wave per channel (b,i); lane = state s.
// h_s <- exp(A_s*dt)*h_s + dt*xc*B[t,s];  y_t = sum_s h_s*C[t,s]
__global__ __launch_bounds__(256) void k_scan(const float* __restrict__ P,
                                              const float* __restrict__ dtT,
                                              const float* __restrict__ xcT,
                                              const float* __restrict__ Alog,
                                              float* __restrict__ yT,
                                              float* __restrict__ hT) {
  const int wid = (blockIdx.x * 256 + threadIdx.x) >> 6;  // 0..4095
  const int lane = threadIdx.x & 63;
  const int b = wid >> 11;
  const float Aneg = -__expf(Alog[lane]);
  const size_t cbase = (size_t)wid * T_;
  const float* pBC = P + (size_t)b * T_ * DP + 2 * DI;  // B at +0, C at +64
  float h = 0.f;
  for (int t0 = 0; t0 < T_; t0 += 64) {
    const float dtv = dtT[cbase + t0 + lane];
    const float xcv = xcT[cbase + t0 + lane];
    const float uvv = dtv * xcv;
    float yv = 0.f;
#pragma unroll
    for (int tm = 0; tm < 64; ++tm) {
      const float sdt = rlane_(dtv, tm);
      const float su = rlane_(uvv, tm);
      const float dA = __expf(Aneg * sdt);
      const float bv = pBC[lane];
      const float cv = pBC[64 + lane];
      h = fmaf(dA, h, su * bv);
      float p = h * cv;
      p += __shfl_xor(p, 1);
      p += __shfl_xor(p, 2);
      p += __shfl_xor(p, 4);
      p += __shfl_xor(p, 8);
      p += __shfl_xor(p, 16);
      p += __shfl_xor(p, 32);
      if (lane == tm) yv = p;
      pBC += DP;
    }
    yT[cbase + t0 + lane] = yv;
  }
  hT[(size_t)wid * DS + lane] = h;
}

// ------------------------------------------------------------- out_proj GEMM
// Out[b,t,d] = sum_i [(yT+D*xcT)*zsT][b,i,t] * W2[d,i]
__global__ __launch_bounds__(256) void k_outproj(const float* __restrict__ yT,
                                                 const float* __restrict__ xcT,
                                                 const float* __restrict__ zsT,
                                                 const float* __restrict__ Dp,
                                                 const float* __restrict__ W2,
                                                 float* __restrict__ Out) {
  __shared__ float As[16][68];
  __shared__ float Bs[16][68];
  const int b = blockIdx.z;
  const int t0 = blockIdx.x * 64, d0 = blockIdx.y * 64;
  const int tid = threadIdx.x;
  const int tm = tid & 15, tn = tid >> 4;
  const int li = tid & 63, rk = tid >> 6;
  const int lr = tid >> 2, lc = (tid & 3) << 2;
  const float* W2p = W2 + (size_t)(d0 + lr) * DI + lc;
  float acc[4][4] = {};
  for (int i0 = 0; i0 < DI; i0 += 16) {
    float a_[4];
#pragma unroll
    for (int q = 0; q < 4; ++q) {
      const int kk = rk + (q << 2);
      const size_t idx = (size_t)(b * DI + i0 + kk) * T_ + t0 + li;
      a_[q] = fmaf(Dp[i0 + kk], xcT[idx], yT[idx]) * zsT[idx];
    }
    const float4 bv = *(const float4*)(W2p + i0);
    __syncthreads();
#pragma unroll
    for (int q = 0; q < 4; ++q) As[rk + (q << 2)][li] = a_[q];
    Bs[lc + 0][lr] = bv.x; Bs[lc + 1][lr] = bv.y;
    Bs[lc + 2][lr] = bv.z; Bs[lc + 3][lr] = bv.w;
    __syncthreads();
#pragma unroll
    for (int kk = 0; kk < 16; ++kk) {
      float aa[4], bb[4];
#pragma unroll
      for (int u = 0; u < 4; ++u) {
        aa[u] = As[kk][(tm << 2) + u];
        bb[u] = Bs[kk][(tn << 2) + u];
      }
#pragma unroll
      for (int mi = 0; mi < 4; ++mi)
#pragma unroll
        for (int ni = 0; ni < 4; ++ni)
          acc[mi][ni] = fmaf(aa[mi], bb[ni], acc[mi][ni]);
    }
  }
  float* Crow = Out + (size_t)b * T_ * DM + (size_t)(t0 + (tm << 2)) * DM + d0 + (tn << 2);
#pragma unroll
  for (int mi = 0; mi < 4; ++mi)
    *(float4*)(Crow + (size_t)mi * DM) =
        make_float4(acc[mi][0], acc[mi][1], acc[mi][2], acc[mi][3]);
}

// ---------------------------------------------------------------------- launch
extern "C" void kernel_launch(void* const* d_in, const int* in_sizes, int n_in,
                              void* d_out, int out_size, void* d_ws, size_t ws_size,
                              hipStream_t stream) {
  const float* x    = (const float*)d_in[0];
  const float* w1   = (const float*)d_in[1];
  const float* cw   = (const float*)d_in[2];
  const float* cb   = (const float*)d_in[3];
  const float* alog = (const float*)d_in[4];
  const float* dpar = (const float*)d_in[5];
  const float* dtw  = (const float*)d_in[6];
  const float* dtb  = (const float*)d_in[7];
  const float* w2   = (const float*)d_in[8];

  float* out = (float*)d_out;
  float* hT  = out + (size_t)B_ * T_ * DM;

  float* ws   = (float*)d_ws;
  float* proj = ws;                                   // 4096*4288
  float* xcT  = proj + (size_t)B_ * T_ * DP;          // 2*2048*2048
  float* zsT  = xcT + (size_t)B_ * DI * T_;
  float* dtT  = zsT + (size_t)B_ * DI * T_;
  float* yT   = dtT + (size_t)B_ * DI * T_;

  k_inproj<<<dim3(64, 67), 256, 0, stream>>>(x, w1, proj);
  k_conv<<<dim3(32, 32, 2), 256, 0, stream>>>(proj, cw, cb, xcT, zsT);
  k_dt<<<dim3(32, 32, 2), 256, 0, stream>>>(proj, dtw, dtb, dtT);
  k_scan<<<dim3(1024), 256, 0, stream>>>(proj, dtT, xcT, alog, yT, hT);
  k_outproj<<<dim3(32, 16, 2), 256, 0, stream>>>(yT, xcT, zsT, dpar, w2, out);
}

// Round 5
// 1230.771 us; speedup vs baseline: 1.4946x; 1.4946x over previous
//
#include <hip/hip_runtime.h>

#define B_  2
#define T_  2048
#define DM  1024
#define DP  4288
#define DI  2048
#define DS  64

typedef short bf16x8 __attribute__((ext_vector_type(8)));
typedef float f32x4 __attribute__((ext_vector_type(4)));

__device__ __forceinline__ float siluf_(float x) { return x / (1.f + __expf(-x)); }
__device__ __forceinline__ float softplusf_(float x) {
  return fmaxf(x, 0.f) + log1pf(__expf(-fabsf(x)));
}
__device__ __forceinline__ float rlane_(float v, int l) {
  return __uint_as_float(__builtin_amdgcn_readlane(__float_as_uint(v), l));
}
__device__ __forceinline__ unsigned short bf16rn_(float f) {
  unsigned u = __float_as_uint(f);
  return (unsigned short)((u + 0x7FFFu + ((u >> 16) & 1u)) >> 16);
}
__device__ __forceinline__ float bf16tof_(unsigned short h) {
  return __uint_as_float((unsigned)h << 16);
}

// ---------------------------------------------------------------- in_proj GEMM
// P[m,n] = sum_k X[m,k]*W[n,k]; M=4096,N=4288,K=1024. bf16x3 split-MFMA:
// a=ah+al (bf16 each); acc += ah*bh + ah*bl + al*bh (al*bl ~2^-16 dropped).
// 4 waves/block, wave = 32x32 (2x2 frags of 16x16x32). k-slot map is applied
// identically to A and B fragments, so any bijective HW k-permutation cancels.
__global__ __launch_bounds__(256) void k_inproj(const float* __restrict__ X,
                                                const float* __restrict__ W,
                                                float* __restrict__ P) {
  __shared__ short Ah[64][40], Al[64][40], Bh[64][40], Bl[64][40];
  const int m0 = blockIdx.x * 64, n0 = blockIdx.y * 64;
  const int tid = threadIdx.x;
  const int lane = tid & 63, w = tid >> 6;
  const int wm = w & 1, wn = w >> 1;
  const int fr = lane & 15, kg = lane >> 4;
  const int sr = tid >> 2, sc = (tid & 3) << 3;  // staging row / col (8 floats)
  const float* Xp = X + (size_t)(m0 + sr) * DM + sc;
  const float* Wp = W + (size_t)(n0 + sr) * DM + sc;
  f32x4 acc[2][2] = {};
  for (int k0 = 0; k0 < DM; k0 += 32) {
    float xa[8], wa[8];
    *(float4*)&xa[0] = *(const float4*)(Xp + k0);
    *(float4*)&xa[4] = *(const float4*)(Xp + k0 + 4);
    *(float4*)&wa[0] = *(const float4*)(Wp + k0);
    *(float4*)&wa[4] = *(const float4*)(Wp + k0 + 4);
    bf16x8 vxh, vxl, vwh, vwl;
#pragma unroll
    for (int j = 0; j < 8; ++j) {
      const unsigned short xh = bf16rn_(xa[j]);
      const unsigned short wh = bf16rn_(wa[j]);
      vxh[j] = (short)xh;
      vwh[j] = (short)wh;
      vxl[j] = (short)bf16rn_(xa[j] - bf16tof_(xh));
      vwl[j] = (short)bf16rn_(wa[j] - bf16tof_(wh));
    }
    __syncthreads();
    *(bf16x8*)&Ah[sr][sc] = vxh;
    *(bf16x8*)&Al[sr][sc] = vxl;
    *(bf16x8*)&Bh[sr][sc] = vwh;
    *(bf16x8*)&Bl[sr][sc] = vwl;
    __syncthreads();
    bf16x8 afh[2], afl[2], bfh[2], bfl[2];
#pragma unroll
    for (int f = 0; f < 2; ++f) {
      const int ar = wm * 32 + f * 16 + fr;
      afh[f] = *(const bf16x8*)&Ah[ar][kg << 3];
      afl[f] = *(const bf16x8*)&Al[ar][kg << 3];
      const int br = wn * 32 + f * 16 + fr;
      bfh[f] = *(const bf16x8*)&Bh[br][kg << 3];
      bfl[f] = *(const bf16x8*)&Bl[br][kg << 3];
    }
#pragma unroll
    for (int fm = 0; fm < 2; ++fm)
#pragma unroll
      for (int fn = 0; fn < 2; ++fn) {
        acc[fm][fn] = __builtin_amdgcn_mfma_f32_16x16x32_bf16(afh[fm], bfh[fn], acc[fm][fn], 0, 0, 0);
        acc[fm][fn] = __builtin_amdgcn_mfma_f32_16x16x32_bf16(afh[fm], bfl[fn], acc[fm][fn], 0, 0, 0);
        acc[fm][fn] = __builtin_amdgcn_mfma_f32_16x16x32_bf16(afl[fm], bfh[fn], acc[fm][fn], 0, 0, 0);
      }
  }
  // C/D layout (measured): col = lane&15, row = (lane>>4)*4 + j
#pragma unroll
  for (int fm = 0; fm < 2; ++fm) {
    const int row = m0 + wm * 32 + fm * 16 + (kg << 2);
#pragma unroll
    for (int fn = 0; fn < 2; ++fn) {
      const int col = n0 + wn * 32 + fn * 16 + fr;
      float* pp = P + (size_t)row * DP + col;
#pragma unroll
      for (int j = 0; j < 4; ++j) pp[(size_t)j * DP] = acc[fm][fn][j];
    }
  }
}

// ------------------------------------------------- depthwise conv + SiLU (+z)
__global__ __launch_bounds__(256) void k_conv(const float* __restrict__ P,
                                              const float* __restrict__ cw,
                                              const float* __restrict__ cb,
                                              float* __restrict__ xcT,
                                              float* __restrict__ zsT) {
  __shared__ float L[64][69];  // [i][r]
  const int b = blockIdx.z;
  const int t0 = blockIdx.x * 64, i0 = blockIdx.y * 64;
  const int tid = threadIdx.x;
  const int li = tid & 63, r0 = tid >> 6;
  const float* pb = P + (size_t)b * T_ * DP;
  for (int r = r0; r < 67; r += 4) {
    const int t = t0 - 3 + r;
    L[li][r] = (t >= 0) ? pb[(size_t)t * DP + i0 + li] : 0.f;
  }
  __syncthreads();
  const int i = tid >> 2, tg = tid & 3;
  const float4 w = *(const float4*)(cw + (size_t)(i0 + i) * 4);
  const float bias = cb[i0 + i];
  float res[16];
#pragma unroll
  for (int j = 0; j < 16; ++j) {
    const int t = (tg << 4) + j;
    float a = bias;
    a = fmaf(w.x, L[i][t + 0], a);
    a = fmaf(w.y, L[i][t + 1], a);
    a = fmaf(w.z, L[i][t + 2], a);
    a = fmaf(w.w, L[i][t + 3], a);
    res[j] = siluf_(a);
  }
  float* dst = xcT + (size_t)(b * DI + i0 + i) * T_ + t0 + (tg << 4);
#pragma unroll
  for (int j = 0; j < 16; j += 4)
    *(float4*)(dst + j) = make_float4(res[j], res[j + 1], res[j + 2], res[j + 3]);

  __syncthreads();
  for (int r = r0; r < 64; r += 4)
    L[li][r] = pb[(size_t)(t0 + r) * DP + DI + i0 + li];
  __syncthreads();
#pragma unroll
  for (int j = 0; j < 16; ++j) res[j] = siluf_(L[i][(tg << 4) + j]);
  float* dst2 = zsT + (size_t)(b * DI + i0 + i) * T_ + t0 + (tg << 4);
#pragma unroll
  for (int j = 0; j < 16; j += 4)
    *(float4*)(dst2 + j) = make_float4(res[j], res[j + 1], res[j + 2], res[j + 3]);
}

// ------------------------------------------------------- delta GEMM + softplus
__global__ __launch_bounds__(256) void k_dt(const float* __restrict__ P,
                                            const float* __restrict__ dtw,
                                            const float* __restrict__ dtb,
                                            float* __restrict__ dtT) {
  __shared__ float As[64][69];  // [t][r]
  __shared__ float Bs[64][69];  // [i][r]
  const int b = blockIdx.z;
  const int t0 = blockIdx.x * 64, i0 = blockIdx.y * 64;
  const int tid = threadIdx.x;
  const int row = tid >> 2, c0 = (tid & 3) << 4;
  const float* pa = P + (size_t)(b * T_ + t0 + row) * DP + (DP - 64) + c0;
  const float* pbm = dtw + (size_t)(i0 + row) * 64 + c0;
#pragma unroll
  for (int j = 0; j < 16; j += 4) {
    *(float4*)&As[row][c0 + j] = *(const float4*)(pa + j);
    *(float4*)&Bs[row][c0 + j] = *(const float4*)(pbm + j);
  }
  __syncthreads();
  const int tm = tid & 15, tn = tid >> 4;
  float acc[4][4] = {};  // [ni][mi]
#pragma unroll 4
  for (int r = 0; r < 64; ++r) {
    float a_[4], b_[4];
#pragma unroll
    for (int u = 0; u < 4; ++u) {
      a_[u] = As[(tm << 2) + u][r];
      b_[u] = Bs[(tn << 2) + u][r];
    }
#pragma unroll
    for (int ni = 0; ni < 4; ++ni)
#pragma unroll
      for (int mi = 0; mi < 4; ++mi)
        acc[ni][mi] = fmaf(a_[mi], b_[ni], acc[ni][mi]);
  }
#pragma unroll
  for (int ni = 0; ni < 4; ++ni) {
    const int i = i0 + (tn << 2) + ni;
    const float bias = dtb[i];
    float4 o;
    o.x = softplusf_(acc[ni][0] + bias);
    o.y = softplusf_(acc[ni][1] + bias);
    o.z = softplusf_(acc[ni][2] + bias);
    o.w = softplusf_(acc[ni][3] + bias);
    *(float4*)&dtT[(size_t)(b * DI + i) * T_ + t0 + (tm << 2)] = o;
  }
}

// ------------------------------------------------------------- selective scan
// ILP rewrite: one wave per channel; lane = state s. B/C chunk staged in LDS
// (shared by the block's 4 same-batch waves); next chunk prefetched to regs
// during compute (async-stage split); unroll-8 groups so exp/mul batch, the
// 8-fma h-chain, and 8 independent butterflies pipeline.
__global__ __launch_bounds__(256, 4) void k_scan(const float* __restrict__ P,
                                                 const float* __restrict__ dtT,
                                                 const float* __restrict__ xcT,
                                                 const float* __restrict__ Alog,
                                                 float* __restrict__ yT,
                                                 float* __restrict__ hT) {
  __shared__ float BC[64][128];  // [t - t0][s] : B at s, C at 64+s
  const int tid = threadIdx.x;
  const int lane = tid & 63;
  const int wid = blockIdx.x * 4 + (tid >> 6);  // 0..4095, batch-uniform/block
  const int b = wid >> 11;
  const float Aneg = -__expf(Alog[lane]);
  const size_t cbase = (size_t)wid * T_;
  const float* pBC0 = P + (size_t)b * T_ * DP + 2 * DI;

  float4 reg[8];
#pragma unroll
  for (int j = 0; j < 8; ++j) {
    const int v = tid + j * 256;  // float4 index in 64x128 tile (32 f4/row)
    reg[j] = *(const float4*)(pBC0 + (size_t)(v >> 5) * DP + ((v & 31) << 2));
  }
#pragma unroll
  for (int j = 0; j < 8; ++j) {
    const int v = tid + j * 256;
    *(float4*)&BC[v >> 5][(v & 31) << 2] = reg[j];
  }
  __syncthreads();

  float h = 0.f;
  for (int t0 = 0; t0 < T_; t0 += 64) {
    const bool more = (t0 + 64) < T_;
    if (more) {
      const float* pn = pBC0 + (size_t)(t0 + 64) * DP;
#pragma unroll
      for (int j = 0; j < 8; ++j) {
        const int v = tid + j * 256;
        reg[j] = *(const float4*)(pn + (size_t)(v >> 5) * DP + ((v & 31) << 2));
      }
    }
    const float dtv = dtT[cbase + t0 + lane];
    const float xcv = xcT[cbase + t0 + lane];
    const float uv = dtv * xcv;
    float yv = 0.f;
#pragma unroll
    for (int g = 0; g < 8; ++g) {
      float dA[8], w[8], cv[8], p[8];
#pragma unroll
      for (int j = 0; j < 8; ++j) {
        const int tm = g * 8 + j;
        const float sdt = rlane_(dtv, tm);
        const float su = rlane_(uv, tm);
        dA[j] = __expf(Aneg * sdt);
        w[j] = su * BC[tm][lane];
        cv[j] = BC[tm][64 + lane];
      }
#pragma unroll
      for (int j = 0; j < 8; ++j) {  // the only serial chain
        h = fmaf(dA[j], h, w[j]);
        p[j] = h * cv[j];
      }
#pragma unroll
      for (int j = 0; j < 8; ++j) {  // 8 independent reduction chains
        float q = p[j];
        q += __shfl_xor(q, 1);
        q += __shfl_xor(q, 2);
        q += __shfl_xor(q, 4);
        q += __shfl_xor(q, 8);
        q += __shfl_xor(q, 16);
        q += __shfl_xor(q, 32);
        if (lane == g * 8 + j) yv = q;
      }
    }
    yT[cbase + t0 + lane] = yv;
    __syncthreads();
    if (more) {
#pragma unroll
      for (int j = 0; j < 8; ++j) {
        const int v = tid + j * 256;
        *(float4*)&BC[v >> 5][(v & 31) << 2] = reg[j];
      }
    }
    __syncthreads();
  }
  hT[(size_t)wid * DS + lane] = h;
}

// ------------------------------------------------------------- out_proj GEMM
__global__ __launch_bounds__(256) void k_outproj(const float* __restrict__ yT,
                                                 const float* __restrict__ xcT,
                                                 const float* __restrict__ zsT,
                                                 const float* __restrict__ Dp,
                                                 const float* __restrict__ W2,
                                                 float* __restrict__ Out) {
  __shared__ float As[16][68];
  __shared__ float Bs[16][68];
  const int b = blockIdx.z;
  const int t0 = blockIdx.x * 64, d0 = blockIdx.y * 64;
  const int tid = threadIdx.x;
  const int tm = tid & 15, tn = tid >> 4;
  const int li = tid & 63, rk = tid >> 6;
  const int lr = tid >> 2, lc = (tid & 3) << 2;
  const float* W2p = W2 + (size_t)(d0 + lr) * DI + lc;
  float acc[4][4] = {};
  for (int i0 = 0; i0 < DI; i0 += 16) {
    float a_[4];
#pragma unroll
    for (int q = 0; q < 4; ++q) {
      const int kk = rk + (q << 2);
      const size_t idx = (size_t)(b * DI + i0 + kk) * T_ + t0 + li;
      a_[q] = fmaf(Dp[i0 + kk], xcT[idx], yT[idx]) * zsT[idx];
    }
    const float4 bv = *(const float4*)(W2p + i0);
    __syncthreads();
#pragma unroll
    for (int q = 0; q < 4; ++q) As[rk + (q << 2)][li] = a_[q];
    Bs[lc + 0][lr] = bv.x; Bs[lc + 1][lr] = bv.y;
    Bs[lc + 2][lr] = bv.z; Bs[lc + 3][lr] = bv.w;
    __syncthreads();
#pragma unroll
    for (int kk = 0; kk < 16; ++kk) {
      float aa[4], bb[4];
#pragma unroll
      for (int u = 0; u < 4; ++u) {
        aa[u] = As[kk][(tm << 2) + u];
        bb[u] = Bs[kk][(tn << 2) + u];
      }
#pragma unroll
      for (int mi = 0; mi < 4; ++mi)
#pragma unroll
        for (int ni = 0; ni < 4; ++ni)
          acc[mi][ni] = fmaf(aa[mi], bb[ni], acc[mi][ni]);
    }
  }
  float* Crow = Out + (size_t)b * T_ * DM + (size_t)(t0 + (tm << 2)) * DM + d0 + (tn << 2);
#pragma unroll
  for (int mi = 0; mi < 4; ++mi)
    *(float4*)(Crow + (size_t)mi * DM) =
        make_float4(acc[mi][0], acc[mi][1], acc[mi][2], acc[mi][3]);
}

// ---------------------------------------------------------------------- launch
extern "C" void kernel_launch(void* const* d_in, const int* in_sizes, int n_in,
                              void* d_out, int out_size, void* d_ws, size_t ws_size,
                              hipStream_t stream) {
  const float* x    = (const float*)d_in[0];
  const float* w1   = (const float*)d_in[1];
  const float* cw   = (const float*)d_in[2];
  const float* cb   = (const float*)d_in[3];
  const float* alog = (const float*)d_in[4];
  const float* dpar = (const float*)d_in[5];
  const float* dtw  = (const float*)d_in[6];
  const float* dtb  = (const float*)d_in[7];
  const float* w2   = (const float*)d_in[8];

  float* out = (float*)d_out;
  float* hT  = out + (size_t)B_ * T_ * DM;

  float* ws   = (float*)d_ws;
  float* proj = ws;                                   // 4096*4288
  float* xcT  = proj + (size_t)B_ * T_ * DP;          // 2*2048*2048
  float* zsT  = xcT + (size_t)B_ * DI * T_;
  float* dtT  = zsT + (size_t)B_ * DI * T_;
  float* yT   = dtT + (size_t)B_ * DI * T_;

  k_inproj<<<dim3(64, 67), 256, 0, stream>>>(x, w1, proj);
  k_conv<<<dim3(32, 32, 2), 256, 0, stream>>>(proj, cw, cb, xcT, zsT);
  k_dt<<<dim3(32, 32, 2), 256, 0, stream>>>(proj, dtw, dtb, dtT);
  k_scan<<<dim3(1024), 256, 0, stream>>>(proj, dtT, xcT, alog, yT, hT);
  k_outproj<<<dim3(32, 16, 2), 256, 0, stream>>>(yT, xcT, zsT, dpar, w2, out);
}

// Round 7
// 1067.330 us; speedup vs baseline: 1.7235x; 1.1531x over previous
//
#include <hip/hip_runtime.h>

#define B_  2
#define T_  2048
#define DM  1024
#define DP  4288
#define DI  2048
#define DS  64

typedef short bf16x8 __attribute__((ext_vector_type(8)));
typedef float f32x4 __attribute__((ext_vector_type(4)));

__device__ __forceinline__ float siluf_(float x) { return x / (1.f + __expf(-x)); }
__device__ __forceinline__ float softplusf_(float x) {
  return fmaxf(x, 0.f) + log1pf(__expf(-fabsf(x)));
}
__device__ __forceinline__ float rlane_(float v, int l) {
  return __uint_as_float(__builtin_amdgcn_readlane(__float_as_uint(v), l));
}
__device__ __forceinline__ unsigned short bf16rn_(float f) {
  unsigned u = __float_as_uint(f);
  return (unsigned short)((u + 0x7FFFu + ((u >> 16) & 1u)) >> 16);
}
__device__ __forceinline__ float bf16tof_(unsigned short h) {
  return __uint_as_float((unsigned)h << 16);
}

// ---------------------------------------------------------------- in_proj GEMM
// (validated round 5: absmax identical to fp32 run)
__global__ __launch_bounds__(256) void k_inproj(const float* __restrict__ X,
                                                const float* __restrict__ W,
                                                float* __restrict__ P) {
  __shared__ short Ah[64][40], Al[64][40], Bh[64][40], Bl[64][40];
  const int m0 = blockIdx.x * 64, n0 = blockIdx.y * 64;
  const int tid = threadIdx.x;
  const int lane = tid & 63, w = tid >> 6;
  const int wm = w & 1, wn = w >> 1;
  const int fr = lane & 15, kg = lane >> 4;
  const int sr = tid >> 2, sc = (tid & 3) << 3;
  const float* Xp = X + (size_t)(m0 + sr) * DM + sc;
  const float* Wp = W + (size_t)(n0 + sr) * DM + sc;
  f32x4 acc[2][2] = {};
  for (int k0 = 0; k0 < DM; k0 += 32) {
    float xa[8], wa[8];
    *(float4*)&xa[0] = *(const float4*)(Xp + k0);
    *(float4*)&xa[4] = *(const float4*)(Xp + k0 + 4);
    *(float4*)&wa[0] = *(const float4*)(Wp + k0);
    *(float4*)&wa[4] = *(const float4*)(Wp + k0 + 4);
    bf16x8 vxh, vxl, vwh, vwl;
#pragma unroll
    for (int j = 0; j < 8; ++j) {
      const unsigned short xh = bf16rn_(xa[j]);
      const unsigned short wh = bf16rn_(wa[j]);
      vxh[j] = (short)xh;
      vwh[j] = (short)wh;
      vxl[j] = (short)bf16rn_(xa[j] - bf16tof_(xh));
      vwl[j] = (short)bf16rn_(wa[j] - bf16tof_(wh));
    }
    __syncthreads();
    *(bf16x8*)&Ah[sr][sc] = vxh;
    *(bf16x8*)&Al[sr][sc] = vxl;
    *(bf16x8*)&Bh[sr][sc] = vwh;
    *(bf16x8*)&Bl[sr][sc] = vwl;
    __syncthreads();
    bf16x8 afh[2], afl[2], bfh[2], bfl[2];
#pragma unroll
    for (int f = 0; f < 2; ++f) {
      const int ar = wm * 32 + f * 16 + fr;
      afh[f] = *(const bf16x8*)&Ah[ar][kg << 3];
      afl[f] = *(const bf16x8*)&Al[ar][kg << 3];
      const int br = wn * 32 + f * 16 + fr;
      bfh[f] = *(const bf16x8*)&Bh[br][kg << 3];
      bfl[f] = *(const bf16x8*)&Bl[br][kg << 3];
    }
#pragma unroll
    for (int fm = 0; fm < 2; ++fm)
#pragma unroll
      for (int fn = 0; fn < 2; ++fn) {
        acc[fm][fn] = __builtin_amdgcn_mfma_f32_16x16x32_bf16(afh[fm], bfh[fn], acc[fm][fn], 0, 0, 0);
        acc[fm][fn] = __builtin_amdgcn_mfma_f32_16x16x32_bf16(afh[fm], bfl[fn], acc[fm][fn], 0, 0, 0);
        acc[fm][fn] = __builtin_amdgcn_mfma_f32_16x16x32_bf16(afl[fm], bfh[fn], acc[fm][fn], 0, 0, 0);
      }
  }
#pragma unroll
  for (int fm = 0; fm < 2; ++fm) {
    const int row = m0 + wm * 32 + fm * 16 + (kg << 2);
#pragma unroll
    for (int fn = 0; fn < 2; ++fn) {
      const int col = n0 + wn * 32 + fn * 16 + fr;
      float* pp = P + (size_t)row * DP + col;
#pragma unroll
      for (int j = 0; j < 4; ++j) pp[(size_t)j * DP] = acc[fm][fn][j];
    }
  }
}

// ------------------------------------------------- depthwise conv + SiLU (+z)
__global__ __launch_bounds__(256) void k_conv(const float* __restrict__ P,
                                              const float* __restrict__ cw,
                                              const float* __restrict__ cb,
                                              float* __restrict__ xcT,
                                              float* __restrict__ zsT) {
  __shared__ float L[64][69];  // [i][r]
  const int b = blockIdx.z;
  const int t0 = blockIdx.x * 64, i0 = blockIdx.y * 64;
  const int tid = threadIdx.x;
  const int li = tid & 63, r0 = tid >> 6;
  const float* pb = P + (size_t)b * T_ * DP;
  for (int r = r0; r < 67; r += 4) {
    const int t = t0 - 3 + r;
    L[li][r] = (t >= 0) ? pb[(size_t)t * DP + i0 + li] : 0.f;
  }
  __syncthreads();
  const int i = tid >> 2, tg = tid & 3;
  const float4 w = *(const float4*)(cw + (size_t)(i0 + i) * 4);
  const float bias = cb[i0 + i];
  float res[16];
#pragma unroll
  for (int j = 0; j < 16; ++j) {
    const int t = (tg << 4) + j;
    float a = bias;
    a = fmaf(w.x, L[i][t + 0], a);
    a = fmaf(w.y, L[i][t + 1], a);
    a = fmaf(w.z, L[i][t + 2], a);
    a = fmaf(w.w, L[i][t + 3], a);
    res[j] = siluf_(a);
  }
  float* dst = xcT + (size_t)(b * DI + i0 + i) * T_ + t0 + (tg << 4);
#pragma unroll
  for (int j = 0; j < 16; j += 4)
    *(float4*)(dst + j) = make_float4(res[j], res[j + 1], res[j + 2], res[j + 3]);

  __syncthreads();
  for (int r = r0; r < 64; r += 4)
    L[li][r] = pb[(size_t)(t0 + r) * DP + DI + i0 + li];
  __syncthreads();
#pragma unroll
  for (int j = 0; j < 16; ++j) res[j] = siluf_(L[i][(tg << 4) + j]);
  float* dst2 = zsT + (size_t)(b * DI + i0 + i) * T_ + t0 + (tg << 4);
#pragma unroll
  for (int j = 0; j < 16; j += 4)
    *(float4*)(dst2 + j) = make_float4(res[j], res[j + 1], res[j + 2], res[j + 3]);
}

// ------------------------------------------------------- delta GEMM + softplus
__global__ __launch_bounds__(256) void k_dt(const float* __restrict__ P,
                                            const float* __restrict__ dtw,
                                            const float* __restrict__ dtb,
                                            float* __restrict__ dtT) {
  __shared__ float As[64][69];  // [t][r]
  __shared__ float Bs[64][69];  // [i][r]
  const int b = blockIdx.z;
  const int t0 = blockIdx.x * 64, i0 = blockIdx.y * 64;
  const int tid = threadIdx.x;
  const int row = tid >> 2, c0 = (tid & 3) << 4;
  const float* pa = P + (size_t)(b * T_ + t0 + row) * DP + (DP - 64) + c0;
  const float* pbm = dtw + (size_t)(i0 + row) * 64 + c0;
#pragma unroll
  for (int j = 0; j < 16; j += 4) {
    *(float4*)&As[row][c0 + j] = *(const float4*)(pa + j);
    *(float4*)&Bs[row][c0 + j] = *(const float4*)(pbm + j);
  }
  __syncthreads();
  const int tm = tid & 15, tn = tid >> 4;
  float acc[4][4] = {};  // [ni][mi]
#pragma unroll 4
  for (int r = 0; r < 64; ++r) {
    float a_[4], b_[4];
#pragma unroll
    for (int u = 0; u < 4; ++u) {
      a_[u] = As[(tm << 2) + u][r];
      b_[u] = Bs[(tn << 2) + u][r];
    }
#pragma unroll
    for (int ni = 0; ni < 4; ++ni)
#pragma unroll
      for (int mi = 0; mi < 4; ++mi)
        acc[ni][mi] = fmaf(a_[mi], b_[ni], acc[ni][mi]);
  }
#pragma unroll
  for (int ni = 0; ni < 4; ++ni) {
    const int i = i0 + (tn << 2) + ni;
    const float bias = dtb[i];
    float4 o;
    o.x = softplusf_(acc[ni][0] + bias);
    o.y = softplusf_(acc[ni][1] + bias);
    o.z = softplusf_(acc[ni][2] + bias);
    o.w = softplusf_(acc[ni][3] + bias);
    *(float4*)&dtT[(size_t)(b * DI + i) * T_ + t0 + (tm << 2)] = o;
  }
}

// ----------------------------------------------------------- B/C compaction
// BCc[b][t][0..64) = B, [64..128) = C  (from proj cols [2*DI, 2*DI+128))
// 2.1 MB total -> L2-resident for the scan's 512x re-reads.
__global__ __launch_bounds__(256) void k_pack(const float* __restrict__ P,
                                              float* __restrict__ BCc) {
  const int idx = blockIdx.x * 256 + threadIdx.x;  // float4 index, 131072 total
  const int b = idx >> 16;
  const int r = idx & 65535;
  const int t = r >> 5;
  const int c = (r & 31) << 2;
  const float4 v = *(const float4*)(P + (size_t)(b * T_ + t) * DP + 2 * DI + c);
  *(float4*)(BCc + ((size_t)idx << 2)) = v;
}

// ------------------------------------------------------------- selective scan
// Same ILP structure as round 5; B/C now from compact BCc (stride 128).
__global__ __launch_bounds__(256, 4) void k_scan(const float* __restrict__ BCc,
                                                 const float* __restrict__ dtT,
                                                 const float* __restrict__ xcT,
                                                 const float* __restrict__ Alog,
                                                 float* __restrict__ yT,
                                                 float* __restrict__ hT) {
  __shared__ float BC[64][128];  // [t - t0][s] : B at s, C at 64+s
  const int tid = threadIdx.x;
  const int lane = tid & 63;
  const int wid = blockIdx.x * 4 + (tid >> 6);  // 0..4095, batch-uniform/block
  const int b = wid >> 11;
  const float Aneg = -__expf(Alog[lane]);
  const size_t cbase = (size_t)wid * T_;
  const float* pBC0 = BCc + (size_t)b * T_ * 128;

  float4 reg[8];
#pragma unroll
  for (int j = 0; j < 8; ++j) {
    const int v = tid + j * 256;  // float4 index in 64x128 tile (32 f4/row)
    reg[j] = *(const float4*)(pBC0 + (size_t)(v >> 5) * 128 + ((v & 31) << 2));
  }
#pragma unroll
  for (int j = 0; j < 8; ++j) {
    const int v = tid + j * 256;
    *(float4*)&BC[v >> 5][(v & 31) << 2] = reg[j];
  }
  __syncthreads();

  float h = 0.f;
  for (int t0 = 0; t0 < T_; t0 += 64) {
    const bool more = (t0 + 64) < T_;
    if (more) {
      const float* pn = pBC0 + (size_t)(t0 + 64) * 128;
#pragma unroll
      for (int j = 0; j < 8; ++j) {
        const int v = tid + j * 256;
        reg[j] = *(const float4*)(pn + (size_t)(v >> 5) * 128 + ((v & 31) << 2));
      }
    }
    const float dtv = dtT[cbase + t0 + lane];
    const float xcv = xcT[cbase + t0 + lane];
    const float uv = dtv * xcv;
    float yv = 0.f;
#pragma unroll
    for (int g = 0; g < 8; ++g) {
      float dA[8], w[8], cv[8], p[8];
#pragma unroll
      for (int j = 0; j < 8; ++j) {
        const int tm = g * 8 + j;
        const float sdt = rlane_(dtv, tm);
        const float su = rlane_(uv, tm);
        dA[j] = __expf(Aneg * sdt);
        w[j] = su * BC[tm][lane];
        cv[j] = BC[tm][64 + lane];
      }
#pragma unroll
      for (int j = 0; j < 8; ++j) {  // the only serial chain
        h = fmaf(dA[j], h, w[j]);
        p[j] = h * cv[j];
      }
#pragma unroll
      for (int j = 0; j < 8; ++j) {  // 8 independent reduction chains
        float q = p[j];
        q += __shfl_xor(q, 1);
        q += __shfl_xor(q, 2);
        q += __shfl_xor(q, 4);
        q += __shfl_xor(q, 8);
        q += __shfl_xor(q, 16);
        q += __shfl_xor(q, 32);
        if (lane == g * 8 + j) yv = q;
      }
    }
    yT[cbase + t0 + lane] = yv;
    __syncthreads();
    if (more) {
#pragma unroll
      for (int j = 0; j < 8; ++j) {
        const int v = tid + j * 256;
        *(float4*)&BC[v >> 5][(v & 31) << 2] = reg[j];
      }
    }
    __syncthreads();
  }
  hT[(size_t)wid * DS + lane] = h;
}

// ------------------------------------------------------------- out_proj GEMM
// Out[b,t,d] = sum_i A'[i,t]*W2[d,i], A' = (y + D*xc)*zs. bf16x3 MFMA,
// tile 64(t) x 128(d), K-step 32; A' computed in staging, transposed to [t][k].
__global__ __launch_bounds__(256) void k_outproj(const float* __restrict__ yT,
                                                 const float* __restrict__ xcT,
                                                 const float* __restrict__ zsT,
                                                 const float* __restrict__ Dp,
                                                 const float* __restrict__ W2,
                                                 float* __restrict__ Out) {
  __shared__ short Ah[64][40], Al[64][40];
  __shared__ short Bh[128][40], Bl[128][40];
  const int b = blockIdx.z;
  const int t0 = blockIdx.x * 64, d0 = blockIdx.y * 128;
  const int tid = threadIdx.x;
  const int lane = tid & 63, w = tid >> 6;
  const int wm = w & 1, wn = w >> 1;          // wave grid 2(t) x 2(d)
  const int fr = lane & 15, kg = lane >> 4;
  const int ai = tid >> 3;                    // A-staging: i-row 0..31
  const int at = (tid & 7) << 3;              //            t-col (8 floats)
  const int dr = tid >> 1;                    // B-staging: d-row 0..127
  const int sc = (tid & 1) << 4;              //            k-col 0 or 16
  f32x4 acc[2][4] = {};
  for (int i0 = 0; i0 < DI; i0 += 32) {
    const size_t idx = (size_t)(b * DI + i0 + ai) * T_ + t0 + at;
    const float dv = Dp[i0 + ai];
    float ya[8], xa[8], za[8], wb[16];
    *(float4*)&ya[0] = *(const float4*)(yT + idx);
    *(float4*)&ya[4] = *(const float4*)(yT + idx + 4);
    *(float4*)&xa[0] = *(const float4*)(xcT + idx);
    *(float4*)&xa[4] = *(const float4*)(xcT + idx + 4);
    *(float4*)&za[0] = *(const float4*)(zsT + idx);
    *(float4*)&za[4] = *(const float4*)(zsT + idx + 4);
    const float* wp = W2 + (size_t)(d0 + dr) * DI + i0 + sc;
    *(float4*)&wb[0]  = *(const float4*)(wp);
    *(float4*)&wb[4]  = *(const float4*)(wp + 4);
    *(float4*)&wb[8]  = *(const float4*)(wp + 8);
    *(float4*)&wb[12] = *(const float4*)(wp + 12);
    bf16x8 vh[2], vl[2];
#pragma unroll
    for (int q = 0; q < 2; ++q)
#pragma unroll
      for (int j = 0; j < 8; ++j) {
        const unsigned short hh = bf16rn_(wb[q * 8 + j]);
        vh[q][j] = (short)hh;
        vl[q][j] = (short)bf16rn_(wb[q * 8 + j] - bf16tof_(hh));
      }
    __syncthreads();
#pragma unroll
    for (int j = 0; j < 8; ++j) {  // A' + convert + transpose-store
      const float a = fmaf(dv, xa[j], ya[j]) * za[j];
      const unsigned short hh = bf16rn_(a);
      Ah[at + j][ai] = (short)hh;
      Al[at + j][ai] = (short)bf16rn_(a - bf16tof_(hh));
    }
    *(bf16x8*)&Bh[dr][sc] = vh[0];
    *(bf16x8*)&Bh[dr][sc + 8] = vh[1];
    *(bf16x8*)&Bl[dr][sc] = vl[0];
    *(bf16x8*)&Bl[dr][sc + 8] = vl[1];
    __syncthreads();
    bf16x8 afh[2], afl[2], bfh[4], bfl[4];
#pragma unroll
    for (int f = 0; f < 2; ++f) {
      const int ar = wm * 32 + f * 16 + fr;
      afh[f] = *(const bf16x8*)&Ah[ar][kg << 3];
      afl[f] = *(const bf16x8*)&Al[ar][kg << 3];
    }
#pragma unroll
    for (int f = 0; f < 4; ++f) {
      const int br = wn * 64 + f * 16 + fr;
      bfh[f] = *(const bf16x8*)&Bh[br][kg << 3];
      bfl[f] = *(const bf16x8*)&Bl[br][kg << 3];
    }
#pragma unroll
    for (int fm = 0; fm < 2; ++fm)
#pragma unroll
      for (int fn = 0; fn < 4; ++fn) {
        acc[fm][fn] = __builtin_amdgcn_mfma_f32_16x16x32_bf16(afh[fm], bfh[fn], acc[fm][fn], 0, 0, 0);
        acc[fm][fn] = __builtin_amdgcn_mfma_f32_16x16x32_bf16(afh[fm], bfl[fn], acc[fm][fn], 0, 0, 0);
        acc[fm][fn] = __builtin_amdgcn_mfma_f32_16x16x32_bf16(afl[fm], bfh[fn], acc[fm][fn], 0, 0, 0);
      }
  }
#pragma unroll
  for (int fm = 0; fm < 2; ++fm) {
    const int row = t0 + wm * 32 + fm * 16 + (kg << 2);
#pragma unroll
    for (int fn = 0; fn < 4; ++fn) {
      const int col = d0 + wn * 64 + fn * 16 + fr;
      float* pp = Out + (size_t)b * T_ * DM + (size_t)row * DM + col;
#pragma unroll
      for (int j = 0; j < 4; ++j) pp[(size_t)j * DM] = acc[fm][fn][j];
    }
  }
}

// ---------------------------------------------------------------------- launch
extern "C" void kernel_launch(void* const* d_in, const int* in_sizes, int n_in,
                              void* d_out, int out_size, void* d_ws, size_t ws_size,
                              hipStream_t stream) {
  const float* x    = (const float*)d_in[0];
  const float* w1   = (const float*)d_in[1];
  const float* cw   = (const float*)d_in[2];
  const float* cb   = (const float*)d_in[3];
  const float* alog = (const float*)d_in[4];
  const float* dpar = (const float*)d_in[5];
  const float* dtw  = (const float*)d_in[6];
  const float* dtb  = (const float*)d_in[7];
  const float* w2   = (const float*)d_in[8];

  float* out = (float*)d_out;
  float* hT  = out + (size_t)B_ * T_ * DM;

  float* ws   = (float*)d_ws;
  float* proj = ws;                                   // 4096*4288
  float* xcT  = proj + (size_t)B_ * T_ * DP;          // 2*2048*2048 each below
  float* zsT  = xcT + (size_t)B_ * DI * T_;
  float* dtT  = zsT + (size_t)B_ * DI * T_;
  float* yT   = dtT + (size_t)B_ * DI * T_;
  float* BCc  = yT + (size_t)B_ * DI * T_;            // 2*2048*128 (2.1 MB)

  k_inproj<<<dim3(64, 67), 256, 0, stream>>>(x, w1, proj);
  k_conv<<<dim3(32, 32, 2), 256, 0, stream>>>(proj, cw, cb, xcT, zsT);
  k_dt<<<dim3(32, 32, 2), 256, 0, stream>>>(proj, dtw, dtb, dtT);
  k_pack<<<dim3(512), 256, 0, stream>>>(proj, BCc);
  k_scan<<<dim3(1024), 256, 0, stream>>>(BCc, dtT, xcT, alog, yT, hT);
  k_outproj<<<dim3(32, 8, 2), 256, 0, stream>>>(yT, xcT, zsT, dpar, w2, out);
}

// Round 9
// 868.178 us; speedup vs baseline: 2.1189x; 1.2294x over previous
//
#include <hip/hip_runtime.h>

#define B_  2
#define T_  2048
#define DM  1024
#define DP  4288
#define DI  2048
#define DS  64

typedef short bf16x8 __attribute__((ext_vector_type(8)));
typedef float f32x4 __attribute__((ext_vector_type(4)));

__device__ __forceinline__ float siluf_(float x) { return x / (1.f + __expf(-x)); }
__device__ __forceinline__ float softplusf_(float x) {
  return fmaxf(x, 0.f) + log1pf(__expf(-fabsf(x)));
}
__device__ __forceinline__ float rlane_(float v, int l) {
  return __uint_as_float(__builtin_amdgcn_readlane(__float_as_uint(v), l));
}
__device__ __forceinline__ unsigned short bf16rn_(float f) {
  unsigned u = __float_as_uint(f);
  return (unsigned short)((u + 0x7FFFu + ((u >> 16) & 1u)) >> 16);
}
__device__ __forceinline__ float bf16tof_(unsigned short h) {
  return __uint_as_float((unsigned)h << 16);
}
// DPP add on the VALU pipe (no LDS op). old=0 + bound_ctrl -> invalid src = 0.
template <int CTRL>
__device__ __forceinline__ float dppadd_(float x) {
  return x + __int_as_float(__builtin_amdgcn_update_dpp(
                 0, __float_as_int(x), CTRL, 0xF, 0xF, true));
}
// canonical GCN wave64 sum; result valid in lane 63
__device__ __forceinline__ float wsum_(float x) {
  x = dppadd_<0x111>(x);  // row_shr:1
  x = dppadd_<0x112>(x);  // row_shr:2
  x = dppadd_<0x114>(x);  // row_shr:4
  x = dppadd_<0x118>(x);  // row_shr:8   -> lane 15+16r = row sum
  x = dppadd_<0x142>(x);  // row_bcast:15
  x = dppadd_<0x143>(x);  // row_bcast:31 -> lane 63 = wave total
  return x;
}

// ---------------------------------------------------------------- in_proj GEMM
// (validated round 5: absmax identical to fp32 run)
__global__ __launch_bounds__(256) void k_inproj(const float* __restrict__ X,
                                                const float* __restrict__ W,
                                                float* __restrict__ P) {
  __shared__ short Ah[64][40], Al[64][40], Bh[64][40], Bl[64][40];
  const int m0 = blockIdx.x * 64, n0 = blockIdx.y * 64;
  const int tid = threadIdx.x;
  const int lane = tid & 63, w = tid >> 6;
  const int wm = w & 1, wn = w >> 1;
  const int fr = lane & 15, kg = lane >> 4;
  const int sr = tid >> 2, sc = (tid & 3) << 3;
  const float* Xp = X + (size_t)(m0 + sr) * DM + sc;
  const float* Wp = W + (size_t)(n0 + sr) * DM + sc;
  f32x4 acc[2][2] = {};
  for (int k0 = 0; k0 < DM; k0 += 32) {
    float xa[8], wa[8];
    *(float4*)&xa[0] = *(const float4*)(Xp + k0);
    *(float4*)&xa[4] = *(const float4*)(Xp + k0 + 4);
    *(float4*)&wa[0] = *(const float4*)(Wp + k0);
    *(float4*)&wa[4] = *(const float4*)(Wp + k0 + 4);
    bf16x8 vxh, vxl, vwh, vwl;
#pragma unroll
    for (int j = 0; j < 8; ++j) {
      const unsigned short xh = bf16rn_(xa[j]);
      const unsigned short wh = bf16rn_(wa[j]);
      vxh[j] = (short)xh;
      vwh[j] = (short)wh;
      vxl[j] = (short)bf16rn_(xa[j] - bf16tof_(xh));
      vwl[j] = (short)bf16rn_(wa[j] - bf16tof_(wh));
    }
    __syncthreads();
    *(bf16x8*)&Ah[sr][sc] = vxh;
    *(bf16x8*)&Al[sr][sc] = vxl;
    *(bf16x8*)&Bh[sr][sc] = vwh;
    *(bf16x8*)&Bl[sr][sc] = vwl;
    __syncthreads();
    bf16x8 afh[2], afl[2], bfh[2], bfl[2];
#pragma unroll
    for (int f = 0; f < 2; ++f) {
      const int ar = wm * 32 + f * 16 + fr;
      afh[f] = *(const bf16x8*)&Ah[ar][kg << 3];
      afl[f] = *(const bf16x8*)&Al[ar][kg << 3];
      const int br = wn * 32 + f * 16 + fr;
      bfh[f] = *(const bf16x8*)&Bh[br][kg << 3];
      bfl[f] = *(const bf16x8*)&Bl[br][kg << 3];
    }
#pragma unroll
    for (int fm = 0; fm < 2; ++fm)
#pragma unroll
      for (int fn = 0; fn < 2; ++fn) {
        acc[fm][fn] = __builtin_amdgcn_mfma_f32_16x16x32_bf16(afh[fm], bfh[fn], acc[fm][fn], 0, 0, 0);
        acc[fm][fn] = __builtin_amdgcn_mfma_f32_16x16x32_bf16(afh[fm], bfl[fn], acc[fm][fn], 0, 0, 0);
        acc[fm][fn] = __builtin_amdgcn_mfma_f32_16x16x32_bf16(afl[fm], bfh[fn], acc[fm][fn], 0, 0, 0);
      }
  }
#pragma unroll
  for (int fm = 0; fm < 2; ++fm) {
    const int row = m0 + wm * 32 + fm * 16 + (kg << 2);
#pragma unroll
    for (int fn = 0; fn < 2; ++fn) {
      const int col = n0 + wn * 32 + fn * 16 + fr;
      float* pp = P + (size_t)row * DP + col;
#pragma unroll
      for (int j = 0; j < 4; ++j) pp[(size_t)j * DP] = acc[fm][fn][j];
    }
  }
}

// ------------------------------------------------- depthwise conv + SiLU (+z)
__global__ __launch_bounds__(256) void k_conv(const float* __restrict__ P,
                                              const float* __restrict__ cw,
                                              const float* __restrict__ cb,
                                              float* __restrict__ xcT,
                                              float* __restrict__ zsT) {
  __shared__ float L[64][69];  // [i][r]
  const int b = blockIdx.z;
  const int t0 = blockIdx.x * 64, i0 = blockIdx.y * 64;
  const int tid = threadIdx.x;
  const int li = tid & 63, r0 = tid >> 6;
  const float* pb = P + (size_t)b * T_ * DP;
  for (int r = r0; r < 67; r += 4) {
    const int t = t0 - 3 + r;
    L[li][r] = (t >= 0) ? pb[(size_t)t * DP + i0 + li] : 0.f;
  }
  __syncthreads();
  const int i = tid >> 2, tg = tid & 3;
  const float4 w = *(const float4*)(cw + (size_t)(i0 + i) * 4);
  const float bias = cb[i0 + i];
  float res[16];
#pragma unroll
  for (int j = 0; j < 16; ++j) {
    const int t = (tg << 4) + j;
    float a = bias;
    a = fmaf(w.x, L[i][t + 0], a);
    a = fmaf(w.y, L[i][t + 1], a);
    a = fmaf(w.z, L[i][t + 2], a);
    a = fmaf(w.w, L[i][t + 3], a);
    res[j] = siluf_(a);
  }
  float* dst = xcT + (size_t)(b * DI + i0 + i) * T_ + t0 + (tg << 4);
#pragma unroll
  for (int j = 0; j < 16; j += 4)
    *(float4*)(dst + j) = make_float4(res[j], res[j + 1], res[j + 2], res[j + 3]);

  __syncthreads();
  for (int r = r0; r < 64; r += 4)
    L[li][r] = pb[(size_t)(t0 + r) * DP + DI + i0 + li];
  __syncthreads();
#pragma unroll
  for (int j = 0; j < 16; ++j) res[j] = siluf_(L[i][(tg << 4) + j]);
  float* dst2 = zsT + (size_t)(b * DI + i0 + i) * T_ + t0 + (tg << 4);
#pragma unroll
  for (int j = 0; j < 16; j += 4)
    *(float4*)(dst2 + j) = make_float4(res[j], res[j + 1], res[j + 2], res[j + 3]);
}

// ------------------------------------------------------- delta GEMM + softplus
__global__ __launch_bounds__(256) void k_dt(const float* __restrict__ P,
                                            const float* __restrict__ dtw,
                                            const float* __restrict__ dtb,
                                            float* __restrict__ dtT) {
  __shared__ float As[64][69];  // [t][r]
  __shared__ float Bs[64][69];  // [i][r]
  const int b = blockIdx.z;
  const int t0 = blockIdx.x * 64, i0 = blockIdx.y * 64;
  const int tid = threadIdx.x;
  const int row = tid >> 2, c0 = (tid & 3) << 4;
  const float* pa = P + (size_t)(b * T_ + t0 + row) * DP + (DP - 64) + c0;
  const float* pbm = dtw + (size_t)(i0 + row) * 64 + c0;
#pragma unroll
  for (int j = 0; j < 16; j += 4) {
    *(float4*)&As[row][c0 + j] = *(const float4*)(pa + j);
    *(float4*)&Bs[row][c0 + j] = *(const float4*)(pbm + j);
  }
  __syncthreads();
  const int tm = tid & 15, tn = tid >> 4;
  float acc[4][4] = {};  // [ni][mi]
#pragma unroll 4
  for (int r = 0; r < 64; ++r) {
    float a_[4], b_[4];
#pragma unroll
    for (int u = 0; u < 4; ++u) {
      a_[u] = As[(tm << 2) + u][r];
      b_[u] = Bs[(tn << 2) + u][r];
    }
#pragma unroll
    for (int ni = 0; ni < 4; ++ni)
#pragma unroll
      for (int mi = 0; mi < 4; ++mi)
        acc[ni][mi] = fmaf(a_[mi], b_[ni], acc[ni][mi]);
  }
#pragma unroll
  for (int ni = 0; ni < 4; ++ni) {
    const int i = i0 + (tn << 2) + ni;
    const float bias = dtb[i];
    float4 o;
    o.x = softplusf_(acc[ni][0] + bias);
    o.y = softplusf_(acc[ni][1] + bias);
    o.z = softplusf_(acc[ni][2] + bias);
    o.w = softplusf_(acc[ni][3] + bias);
    *(float4*)&dtT[(size_t)(b * DI + i) * T_ + t0 + (tm << 2)] = o;
  }
}

// ----------------------------------------------------------- B/C compaction
// BCc[b][t][0..64) = B, [64..128) = C  (dense; measured round 7)
__global__ __launch_bounds__(256) void k_pack(const float* __restrict__ P,
                                              float* __restrict__ BCc) {
  const int idx = blockIdx.x * 256 + threadIdx.x;  // float4 index, 131072 total
  const int b = idx >> 16;
  const int r = idx & 65535;
  const int t = r >> 5;
  const int c = (r & 31) << 2;
  const float4 v = *(const float4*)(P + (size_t)(b * T_ + t) * DP + 2 * DI + c);
  *(float4*)(BCc + ((size_t)idx << 2)) = v;
}

// ------------------------------------------------------------- selective scan
// Round-7 structure, ONE delta: the 6-deep ds_bpermute butterfly is replaced
// by a DPP wave-sum on the VALU pipe. LDS ops/step: 8 -> 2 (conflict-free
// stride-1 b32 reads of B and C planes).
__global__ __launch_bounds__(256, 4) void k_scan(const float* __restrict__ BCc,
                                                 const float* __restrict__ dtT,
                                                 const float* __restrict__ xcT,
                                                 const float* __restrict__ Alog,
                                                 float* __restrict__ yT,
                                                 float* __restrict__ hT) {
  __shared__ float BC[64][128];  // [t - t0][s] : B at s, C at 64+s
  const int tid = threadIdx.x;
  const int lane = tid & 63;
  const int wid = blockIdx.x * 4 + (tid >> 6);  // batch-uniform per block
  const int b = wid >> 11;
  const float Aneg = -__expf(Alog[lane]);
  const size_t cbase = (size_t)wid * T_;
  const float* pBC0 = BCc + (size_t)b * T_ * 128;

  float4 reg[8];
#pragma unroll
  for (int j = 0; j < 8; ++j) {
    const int v = tid + j * 256;  // float4 index in 64x128 tile (32 f4/row)
    reg[j] = *(const float4*)(pBC0 + (size_t)(v >> 5) * 128 + ((v & 31) << 2));
  }
#pragma unroll
  for (int j = 0; j < 8; ++j) {
    const int v = tid + j * 256;
    *(float4*)&BC[v >> 5][(v & 31) << 2] = reg[j];
  }
  __syncthreads();

  float h = 0.f;
  for (int t0 = 0; t0 < T_; t0 += 64) {
    const bool more = (t0 + 64) < T_;
    if (more) {
      const float* pn = pBC0 + (size_t)(t0 + 64) * 128;
#pragma unroll
      for (int j = 0; j < 8; ++j) {
        const int v = tid + j * 256;
        reg[j] = *(const float4*)(pn + (size_t)(v >> 5) * 128 + ((v & 31) << 2));
      }
    }
    const float dtv = dtT[cbase + t0 + lane];
    const float xcv = xcT[cbase + t0 + lane];
    const float uv = dtv * xcv;
    float yv = 0.f;
#pragma unroll
    for (int g = 0; g < 8; ++g) {
      float dA[8], w[8], cv[8], p[8];
#pragma unroll
      for (int j = 0; j < 8; ++j) {
        const int tm = g * 8 + j;
        const float sdt = rlane_(dtv, tm);
        const float su = rlane_(uv, tm);
        dA[j] = __expf(Aneg * sdt);
        w[j] = su * BC[tm][lane];
        cv[j] = BC[tm][64 + lane];
      }
#pragma unroll
      for (int j = 0; j < 8; ++j) {  // the only serial chain
        h = fmaf(dA[j], h, w[j]);
        p[j] = h * cv[j];
      }
#pragma unroll
      for (int j = 0; j < 8; ++j) {  // 8 independent DPP chains (VALU pipe)
        const float q = wsum_(p[j]);
        const float ys = rlane_(q, 63);
        if (lane == g * 8 + j) yv = ys;
      }
    }
    yT[cbase + t0 + lane] = yv;
    __syncthreads();
    if (more) {
#pragma unroll
      for (int j = 0; j < 8; ++j) {
        const int v = tid + j * 256;
        *(float4*)&BC[v >> 5][(v & 31) << 2] = reg[j];
      }
    }
    __syncthreads();
  }
  hT[(size_t)wid * DS + lane] = h;
}

// ------------------------------------------------------------- out_proj GEMM
__global__ __launch_bounds__(256) void k_outproj(const float* __restrict__ yT,
                                                 const float* __restrict__ xcT,
                                                 const float* __restrict__ zsT,
                                                 const float* __restrict__ Dp,
                                                 const float* __restrict__ W2,
                                                 float* __restrict__ Out) {
  __shared__ short Ah[64][40], Al[64][40];
  __shared__ short Bh[128][40], Bl[128][40];
  const int b = blockIdx.z;
  const int t0 = blockIdx.x * 64, d0 = blockIdx.y * 128;
  const int tid = threadIdx.x;
  const int lane = tid & 63, w = tid >> 6;
  const int wm = w & 1, wn = w >> 1;          // wave grid 2(t) x 2(d)
  const int fr = lane & 15, kg = lane >> 4;
  const int ai = tid >> 3;                    // A-staging: i-row 0..31
  const int at = (tid & 7) << 3;              //            t-col (8 floats)
  const int dr = tid >> 1;                    // B-staging: d-row 0..127
  const int sc = (tid & 1) << 4;              //            k-col 0 or 16
  f32x4 acc[2][4] = {};
  for (int i0 = 0; i0 < DI; i0 += 32) {
    const size_t idx = (size_t)(b * DI + i0 + ai) * T_ + t0 + at;
    const float dv = Dp[i0 + ai];
    float ya[8], xa[8], za[8], wb[16];
    *(float4*)&ya[0] = *(const float4*)(yT + idx);
    *(float4*)&ya[4] = *(const float4*)(yT + idx + 4);
    *(float4*)&xa[0] = *(const float4*)(xcT + idx);
    *(float4*)&xa[4] = *(const float4*)(xcT + idx + 4);
    *(float4*)&za[0] = *(const float4*)(zsT + idx);
    *(float4*)&za[4] = *(const float4*)(zsT + idx + 4);
    const float* wp = W2 + (size_t)(d0 + dr) * DI + i0 + sc;
    *(float4*)&wb[0]  = *(const float4*)(wp);
    *(float4*)&wb[4]  = *(const float4*)(wp + 4);
    *(float4*)&wb[8]  = *(const float4*)(wp + 8);
    *(float4*)&wb[12] = *(const float4*)(wp + 12);
    bf16x8 vh[2], vl[2];
#pragma unroll
    for (int q = 0; q < 2; ++q)
#pragma unroll
      for (int j = 0; j < 8; ++j) {
        const unsigned short hh = bf16rn_(wb[q * 8 + j]);
        vh[q][j] = (short)hh;
        vl[q][j] = (short)bf16rn_(wb[q * 8 + j] - bf16tof_(hh));
      }
    __syncthreads();
#pragma unroll
    for (int j = 0; j < 8; ++j) {  // A' + convert + transpose-store
      const float a = fmaf(dv, xa[j], ya[j]) * za[j];
      const unsigned short hh = bf16rn_(a);
      Ah[at + j][ai] = (short)hh;
      Al[at + j][ai] = (short)bf16rn_(a - bf16tof_(hh));
    }
    *(bf16x8*)&Bh[dr][sc] = vh[0];
    *(bf16x8*)&Bh[dr][sc + 8] = vh[1];
    *(bf16x8*)&Bl[dr][sc] = vl[0];
    *(bf16x8*)&Bl[dr][sc + 8] = vl[1];
    __syncthreads();
    bf16x8 afh[2], afl[2], bfh[4], bfl[4];
#pragma unroll
    for (int f = 0; f < 2; ++f) {
      const int ar = wm * 32 + f * 16 + fr;
      afh[f] = *(const bf16x8*)&Ah[ar][kg << 3];
      afl[f] = *(const bf16x8*)&Al[ar][kg << 3];
    }
#pragma unroll
    for (int f = 0; f < 4; ++f) {
      const int br = wn * 64 + f * 16 + fr;
      bfh[f] = *(const bf16x8*)&Bh[br][kg << 3];
      bfl[f] = *(const bf16x8*)&Bl[br][kg << 3];
    }
#pragma unroll
    for (int fm = 0; fm < 2; ++fm)
#pragma unroll
      for (int fn = 0; fn < 4; ++fn) {
        acc[fm][fn] = __builtin_amdgcn_mfma_f32_16x16x32_bf16(afh[fm], bfh[fn], acc[fm][fn], 0, 0, 0);
        acc[fm][fn] = __builtin_amdgcn_mfma_f32_16x16x32_bf16(afh[fm], bfl[fn], acc[fm][fn], 0, 0, 0);
        acc[fm][fn] = __builtin_amdgcn_mfma_f32_16x16x32_bf16(afl[fm], bfh[fn], acc[fm][fn], 0, 0, 0);
      }
  }
#pragma unroll
  for (int fm = 0; fm < 2; ++fm) {
    const int row = t0 + wm * 32 + fm * 16 + (kg << 2);
#pragma unroll
    for (int fn = 0; fn < 4; ++fn) {
      const int col = d0 + wn * 64 + fn * 16 + fr;
      float* pp = Out + (size_t)b * T_ * DM + (size_t)row * DM + col;
#pragma unroll
      for (int j = 0; j < 4; ++j) pp[(size_t)j * DM] = acc[fm][fn][j];
    }
  }
}

// ---------------------------------------------------------------------- launch
extern "C" void kernel_launch(void* const* d_in, const int* in_sizes, int n_in,
                              void* d_out, int out_size, void* d_ws, size_t ws_size,
                              hipStream_t stream) {
  const float* x    = (const float*)d_in[0];
  const float* w1   = (const float*)d_in[1];
  const float* cw   = (const float*)d_in[2];
  const float* cb   = (const float*)d_in[3];
  const float* alog = (const float*)d_in[4];
  const float* dpar = (const float*)d_in[5];
  const float* dtw  = (const float*)d_in[6];
  const float* dtb  = (const float*)d_in[7];
  const float* w2   = (const float*)d_in[8];

  float* out = (float*)d_out;
  float* hT  = out + (size_t)B_ * T_ * DM;

  float* ws   = (float*)d_ws;
  float* proj = ws;                                   // 4096*4288
  float* xcT  = proj + (size_t)B_ * T_ * DP;          // 2*2048*2048 each below
  float* zsT  = xcT + (size_t)B_ * DI * T_;
  float* dtT  = zsT + (size_t)B_ * DI * T_;
  float* yT   = dtT + (size_t)B_ * DI * T_;
  float* BCc  = yT + (size_t)B_ * DI * T_;            // 2*2048*128 (2.1 MB)

  k_inproj<<<dim3(64, 67), 256, 0, stream>>>(x, w1, proj);
  k_conv<<<dim3(32, 32, 2), 256, 0, stream>>>(proj, cw, cb, xcT, zsT);
  k_dt<<<dim3(32, 32, 2), 256, 0, stream>>>(proj, dtw, dtb, dtT);
  k_pack<<<dim3(512), 256, 0, stream>>>(proj, BCc);
  k_scan<<<dim3(1024), 256, 0, stream>>>(BCc, dtT, xcT, alog, yT, hT);
  k_outproj<<<dim3(32, 8, 2), 256, 0, stream>>>(yT, xcT, zsT, dpar, w2, out);
}